// Round 18
// baseline (326.780 us; speedup 1.0000x reference)
//
#include <hip/hip_runtime.h>
#include <hip/hip_bf16.h>
#include <hip/hip_fp16.h>

// GCN3: 3-layer GCN on MI355X. All internal feature matrices fp16 (f32 accumulate).
// out[i] = dinv[i]*(sum_e ew*Ts[row_e] + Ts[i]) + b, Ts[r] = dinv[r]*(h@W)[r]
// CSC build: LDS multi-split (256-node buckets) -> parallel column scan ->
// per-bucket counting sort -> canonical bitonic sort (bit-deterministic).
// GEMMs: fp16-input MFMA, LDS XOR-swizzled fragments.
// This round: layer-1 agg = unroll-8 (A/B) vs layer-2 unroll-4 control;
// weight transpose fused into mhist launch.

#define K_DIM 128
#define EPB 4096    // edges per multi-split block
#define BSH 8       // bucket shift: 256 nodes per bucket
#define NBMAX 512   // LDS array size for bucket counters

using h4 = __attribute__((ext_vector_type(4))) _Float16;
using h8 = __attribute__((ext_vector_type(8))) _Float16;
using f16x4 = h4;
using f16x8 = h8;
typedef float f32x4 __attribute__((ext_vector_type(4)));

// ---------------- per-block bucket histogram (LDS) + fused weight transpose ----------
__global__ __launch_bounds__(256) void mhist_kernel(const int* __restrict__ col,
                                                    int* __restrict__ Hm, int e, int nb,
                                                    int nblk,
                                                    const float* __restrict__ W1,
                                                    const float* __restrict__ W2,
                                                    const float* __restrict__ W3,
                                                    _Float16* __restrict__ Wt1,
                                                    _Float16* __restrict__ Wt2,
                                                    _Float16* __restrict__ Wt3) {
    int blk = blockIdx.x, t = threadIdx.x;
    if (blk >= nblk) {   // weight transpose blocks
        int i = (blk - nblk) * 256 + t;
        if (i < 16384) {
            int k = i / 128, c = i % 128;
            Wt1[c * 128 + k] = (_Float16)W1[i];
        } else if (i < 32768) {
            int j = i - 16384, k = j / 128, c = j % 128;
            Wt2[c * 128 + k] = (_Float16)W2[j];
        } else if (i < 40960) {
            int j = i - 32768, k = j / 64, c = j % 64;
            Wt3[c * 128 + k] = (_Float16)W3[j];
        }
        return;
    }
    __shared__ int lcnt[NBMAX];
    for (int i = t; i < nb; i += 256) lcnt[i] = 0;
    __syncthreads();
    int base = blk * EPB, end = min(base + EPB, e);
    for (int i = base + t; i < end; i += 256) atomicAdd(&lcnt[col[i] >> BSH], 1);
    __syncthreads();
    for (int i = t; i < nb; i += 256) Hm[(size_t)blk * nb + i] = lcnt[i];
}

// ---------------- column scan: per bucket, exclusive scan over blocks (one wave/col) ----
__global__ __launch_bounds__(256) void colscan_kernel(int* __restrict__ Hm,
                                                      int* __restrict__ bcnt,
                                                      int nblk, int nb) {
    int t = blockIdx.x * 4 + (threadIdx.x >> 6);   // bucket column
    int lane = threadIdx.x & 63;
    if (t >= nb) return;
    int carry = 0;
    for (int c0 = 0; c0 < nblk; c0 += 64) {
        int b = c0 + lane;
        int x = (b < nblk) ? Hm[(size_t)b * nb + t] : 0;
        int v = x;
        #pragma unroll
        for (int d = 1; d < 64; d <<= 1) {
            int y = __shfl_up(v, d, 64);
            if (lane >= d) v += y;
        }
        if (b < nblk) Hm[(size_t)b * nb + t] = carry + v - x;  // exclusive within column
        carry += __shfl(v, 63, 64);
    }
    if (lane == 0) bcnt[t] = carry;   // bucket total
}

// ---------------- single-block scan of bucket totals -> bptr ----------------
__global__ __launch_bounds__(1024) void bscan2_kernel(const int* __restrict__ bcnt,
                                                      int* __restrict__ bptr,
                                                      int* __restrict__ nodeptr,
                                                      int nb, int nN, int etot) {
    __shared__ int wsum[16];
    int t = threadIdx.x, lane = t & 63, wid = t >> 6;
    int x = (t < nb) ? bcnt[t] : 0;
    int v = x;
    #pragma unroll
    for (int d = 1; d < 64; d <<= 1) {
        int y = __shfl_up(v, d, 64);
        if (lane >= d) v += y;
    }
    if (lane == 63) wsum[wid] = v;
    __syncthreads();
    if (wid == 0) {
        int s = (lane < 16) ? wsum[lane] : 0;
        #pragma unroll
        for (int d = 1; d < 16; d <<= 1) {
            int y = __shfl_up(s, d, 64);
            if (lane >= d) s += y;
        }
        if (lane < 16) wsum[lane] = s;
    }
    __syncthreads();
    int woff = (wid > 0) ? wsum[wid - 1] : 0;
    if (t < nb) bptr[t] = v + woff - x;
    if (t == 0) { bptr[nb] = etot; nodeptr[nN] = etot; }
}

// ---------------- multi-split scatter (bptr folded in): bucket-grouped writes ----
__global__ __launch_bounds__(256) void mscatter_kernel(const int* __restrict__ row,
                                                       const int* __restrict__ col,
                                                       const float* __restrict__ ew,
                                                       const int* __restrict__ Hm,
                                                       const int* __restrict__ bptr,
                                                       int2* __restrict__ ebuf,
                                                       int e, int nb) {
    __shared__ int2 sbuf[EPB];               // 32 KB
    __shared__ unsigned short sbkt[EPB];     // 8 KB
    __shared__ int lcnt[NBMAX], lbase[NBMAX], lfill[NBMAX], garr[NBMAX];  // 8 KB
    int blk = blockIdx.x, t = threadIdx.x, lane = t & 63, wid = t >> 6;
    int base = blk * EPB, end = min(base + EPB, e);
    int cnt = end - base;
    if (cnt <= 0) return;
    for (int i = t; i < nb; i += 256) {
        garr[i] = Hm[(size_t)blk * nb + i] + bptr[i];   // fold global bucket base
        lcnt[i] = 0;
    }
    __syncthreads();
    for (int i = base + t; i < end; i += 256) atomicAdd(&lcnt[col[i] >> BSH], 1);
    __syncthreads();
    if (wid == 0) {   // wave-0 exclusive scan of lcnt -> lbase/lfill
        int carry = 0;
        for (int c0 = 0; c0 < nb; c0 += 64) {
            int idx = c0 + lane;
            int x = (idx < nb) ? lcnt[idx] : 0;
            int v = x;
            #pragma unroll
            for (int d = 1; d < 64; d <<= 1) {
                int y = __shfl_up(v, d, 64);
                if (lane >= d) v += y;
            }
            if (idx < nb) { lbase[idx] = carry + v - x; lfill[idx] = carry + v - x; }
            carry += __shfl(v, 63, 64);
        }
    }
    __syncthreads();
    for (int i = base + t; i < end; i += 256) {
        int c = col[i];
        int b = c >> BSH;
        int p = atomicAdd(&lfill[b], 1);
        sbuf[p] = make_int2(row[i] | ((c & 255) << 20), __float_as_int(ew[i]));
        sbkt[p] = (unsigned short)b;
    }
    __syncthreads();
    for (int j = t; j < cnt; j += 256) {   // bucket-grouped contiguous runs
        int b = sbkt[j];
        ebuf[garr[b] + (j - lbase[b])] = sbuf[j];
    }
}

// ---------------- per-bucket counting sort (256 bins) into final CSC + node ptr ----------
__global__ __launch_bounds__(256) void bbuild_kernel(const int2* __restrict__ ebuf,
                                                     const int* __restrict__ bptr,
                                                     int2* __restrict__ csr,
                                                     int* __restrict__ ptr, int n) {
    __shared__ int cnt[256];
    __shared__ int fil[256];
    __shared__ int wtot[4];
    int b = blockIdx.x, t = threadIdx.x, lane = t & 63, wid = t >> 6;
    int s = bptr[b], e = bptr[b + 1];
    cnt[t] = 0;
    __syncthreads();
    for (int k = s + t; k < e; k += 256) atomicAdd(&cnt[(ebuf[k].x >> 20) & 255], 1);
    __syncthreads();
    int x = cnt[t];
    int v = x;
    #pragma unroll
    for (int d = 1; d < 64; d <<= 1) {
        int y = __shfl_up(v, d, 64);
        if (lane >= d) v += y;
    }
    if (lane == 63) wtot[wid] = v;
    __syncthreads();
    int woff = 0;
    for (int j = 0; j < wid; ++j) woff += wtot[j];
    int excl = woff + v - x;
    fil[t] = excl;
    int node = b * 256 + t;
    if (node < n) ptr[node] = s + excl;
    __syncthreads();
    for (int k = s + t; k < e; k += 256) {
        int2 vv = ebuf[k];
        int c = (vv.x >> 20) & 255;
        int p = atomicAdd(&fil[c], 1);
        csr[s + p] = make_int2(vv.x & 0xFFFFF, vv.y);
    }
}

// ---------------- canonicalize + dinv: one wave per node, bitonic in-register sort ----
__global__ __launch_bounds__(256) void sortdeg_kernel(int2* __restrict__ csr,
                                                      const int* __restrict__ ptr,
                                                      float* __restrict__ dinv, int n) {
    int node = blockIdx.x * 4 + (threadIdx.x >> 6);
    int lane = threadIdx.x & 63;
    if (node >= n) return;
    int s = ptr[node], e = ptr[node + 1];
    int len = e - s;
    if (len <= 64) {
        int mx = 0x7FFFFFFF;
        unsigned my = 0xFFFFFFFFu;   // sentinel = +inf key
        if (lane < len) {
            int2 v = csr[s + lane];
            mx = v.x; my = (unsigned)v.y;
        }
        #pragma unroll
        for (int k = 2; k <= 64; k <<= 1) {
            #pragma unroll
            for (int j = k >> 1; j > 0; j >>= 1) {
                int ox = __shfl_xor(mx, j, 64);
                unsigned oy = (unsigned)__shfl_xor((int)my, j, 64);
                bool up = ((lane & k) == 0);
                bool lower = ((lane & j) == 0);
                bool keep_min = (up == lower);
                bool me_gt  = (mx > ox) || (mx == ox && my > oy);
                bool oth_gt = (ox > mx) || (ox == mx && oy > my);
                bool take = keep_min ? me_gt : oth_gt;
                if (take) { mx = ox; my = oy; }
            }
        }
        if (lane < len) csr[s + lane] = make_int2(mx, (int)my);
        float w = (lane < len) ? __uint_as_float(my) : 0.f;
        #pragma unroll
        for (int d = 32; d; d >>= 1) w += __shfl_xor(w, d, 64);
        if (lane == 0) dinv[node] = rsqrtf(1.0f + w);
    } else {
        if (lane == 0) {  // ultra-rare fallback
            for (int k = s + 1; k < e; ++k) {
                int2 key = csr[k];
                int j = k - 1;
                while (j >= s) {
                    int2 cj = csr[j];
                    bool gt = (cj.x > key.x) ||
                              (cj.x == key.x && (unsigned)cj.y > (unsigned)key.y);
                    if (!gt) break;
                    csr[j + 1] = cj;
                    --j;
                }
                csr[j + 1] = key;
            }
            float sum = 1.0f;
            for (int k = s; k < e; ++k) sum += __int_as_float(csr[k].y);
            dinv[node] = rsqrtf(sum);
        }
    }
}

// ---------------- MFMA GEMM: Ts[r,:] = dinv[r] * (A[r,:] @ W) ----------------
template <int DOUT, bool FP16IN>
__global__ __launch_bounds__(256) void mgemm_kernel(const void* __restrict__ Ap,
                                                    const _Float16* __restrict__ Wt,
                                                    const float* __restrict__ dinv,
                                                    _Float16* __restrict__ Tout, int nrows) {
    constexpr int BM = 128;
    constexpr int NCB = DOUT / 16;
    __shared__ f16x8 Als[BM * 16];
    __shared__ f16x8 Wls[DOUT * 16];
    int t = threadIdx.x;
    int row0 = blockIdx.x * BM;

    const f16x8* Wt8 = (const f16x8*)Wt;
    for (int i = t; i < DOUT * 16; i += 256) {
        int r = i >> 4, s = i & 15;
        Wls[r * 16 + (s ^ (r & 7))] = Wt8[i];
    }
    if constexpr (FP16IN) {
        const f16x8* A8 = (const f16x8*)Ap;
        for (int i = t; i < BM * 16; i += 256) {
            int r = i >> 4, s = i & 15;
            f16x8 v = {};
            int gr = row0 + r;
            if (gr < nrows) v = A8[(size_t)gr * 16 + s];
            Als[r * 16 + (s ^ (r & 7))] = v;
        }
    } else {
        const float* A = (const float*)Ap;
        f16x4* Als4 = (f16x4*)Als;
        for (int i = t; i < BM * 32; i += 256) {
            int r = i >> 5, c4 = i & 31;
            float4 v = make_float4(0.f, 0.f, 0.f, 0.f);
            int gr = row0 + r;
            if (gr < nrows) v = ((const float4*)(A + (size_t)gr * 128))[c4];
            f16x4 h;
            h[0] = (_Float16)v.x; h[1] = (_Float16)v.y;
            h[2] = (_Float16)v.z; h[3] = (_Float16)v.w;
            Als4[r * 32 + (c4 ^ ((r & 7) << 1))] = h;
        }
    }
    __syncthreads();

    int w = t >> 6, l = t & 63;
    int lcol = l & 15, lk = l >> 4;
    int wr0 = w * 32;

    f16x8 af[2][4];
    #pragma unroll
    for (int rb = 0; rb < 2; ++rb) {
        int r = wr0 + rb * 16 + lcol;
        #pragma unroll
        for (int kc = 0; kc < 4; ++kc) {
            int s = kc * 4 + lk;
            af[rb][kc] = Als[r * 16 + (s ^ (r & 7))];
        }
    }

    f32x4 acc[2][NCB] = {};
    #pragma unroll
    for (int cb = 0; cb < NCB; ++cb) {
        int c = cb * 16 + lcol;
        f16x8 bf[4];
        #pragma unroll
        for (int kc = 0; kc < 4; ++kc) {
            int s = kc * 4 + lk;
            bf[kc] = Wls[c * 16 + (s ^ (c & 7))];
        }
        #pragma unroll
        for (int rb = 0; rb < 2; ++rb) {
            #pragma unroll
            for (int kc = 0; kc < 4; ++kc)
                acc[rb][cb] = __builtin_amdgcn_mfma_f32_16x16x32_f16(
                    af[rb][kc], bf[kc], acc[rb][cb], 0, 0, 0);
        }
    }

    #pragma unroll
    for (int rb = 0; rb < 2; ++rb) {
        #pragma unroll
        for (int reg = 0; reg < 4; ++reg) {
            int gr = row0 + wr0 + rb * 16 + lk * 4 + reg;
            if (gr >= nrows) continue;
            float di = dinv[gr];
            #pragma unroll
            for (int cb = 0; cb < NCB; ++cb) {
                int c = cb * 16 + lcol;
                Tout[(size_t)gr * DOUT + c] = (_Float16)(acc[rb][cb][reg] * di);
            }
        }
    }
}

// ---------------- aggregation, D=128: 16 lanes/node; UNROLL = 4 (control) or 8 (test) ----
template <int UNROLL>
__global__ __launch_bounds__(256) void agg128_kernel(const _Float16* __restrict__ T,
                                                     const int* __restrict__ ptr,
                                                     const int2* __restrict__ csr,
                                                     const float* __restrict__ dinv,
                                                     const float* __restrict__ bias,
                                                     _Float16* __restrict__ out, int n) {
    int node = blockIdx.x * 16 + (threadIdx.x >> 4);
    int g = threadIdx.x & 15;
    if (node >= n) return;
    int s = ptr[node], e = ptr[node + 1];
    float di = dinv[node];
    const h8* Tv = (const h8*)T;
    float acc[8] = {};
    int k = s;
    if constexpr (UNROLL == 8) {
        for (; k + 7 < e; k += 8) {
            int2 ed[8];
            h8 vv[8];
            #pragma unroll
            for (int u = 0; u < 8; ++u) ed[u] = csr[k + u];
            #pragma unroll
            for (int u = 0; u < 8; ++u) vv[u] = Tv[(size_t)ed[u].x * 16 + g];
            #pragma unroll
            for (int u = 0; u < 8; ++u) {
                float w = __int_as_float(ed[u].y);
                #pragma unroll
                for (int j = 0; j < 8; ++j) acc[j] += w * (float)vv[u][j];
            }
        }
    }
    for (; k + 3 < e; k += 4) {
        int2 e0 = csr[k], e1 = csr[k + 1], e2 = csr[k + 2], e3 = csr[k + 3];
        h8 v0 = Tv[(size_t)e0.x * 16 + g];
        h8 v1 = Tv[(size_t)e1.x * 16 + g];
        h8 v2 = Tv[(size_t)e2.x * 16 + g];
        h8 v3 = Tv[(size_t)e3.x * 16 + g];
        float w0 = __int_as_float(e0.y), w1 = __int_as_float(e1.y);
        float w2 = __int_as_float(e2.y), w3 = __int_as_float(e3.y);
        #pragma unroll
        for (int j = 0; j < 8; ++j) acc[j] += w0 * (float)v0[j];
        #pragma unroll
        for (int j = 0; j < 8; ++j) acc[j] += w1 * (float)v1[j];
        #pragma unroll
        for (int j = 0; j < 8; ++j) acc[j] += w2 * (float)v2[j];
        #pragma unroll
        for (int j = 0; j < 8; ++j) acc[j] += w3 * (float)v3[j];
    }
    for (; k < e; ++k) {
        int2 e0 = csr[k];
        h8 v0 = Tv[(size_t)e0.x * 16 + g];
        float w0 = __int_as_float(e0.y);
        #pragma unroll
        for (int j = 0; j < 8; ++j) acc[j] += w0 * (float)v0[j];
    }
    h8 hs = Tv[(size_t)node * 16 + g];  // self term: + Ts[i]
    #pragma unroll
    for (int j = 0; j < 8; ++j) acc[j] += (float)hs[j];
    float4 b0 = ((const float4*)bias)[g * 2];
    float4 b1 = ((const float4*)bias)[g * 2 + 1];
    float bb[8] = {b0.x, b0.y, b0.z, b0.w, b1.x, b1.y, b1.z, b1.w};
    h8 o;
    #pragma unroll
    for (int j = 0; j < 8; ++j) {
        float v = di * acc[j] + bb[j];
        o[j] = (_Float16)fmaxf(v, 0.f);   // relu
    }
    ((h8*)out)[(size_t)node * 16 + g] = o;
}

// ---------------- aggregation, D=64 fp16 T -> f32 out (layer 3): 8 lanes/node ----
__global__ __launch_bounds__(256) void agg64_kernel(const _Float16* __restrict__ T,
                                                    const int* __restrict__ ptr,
                                                    const int2* __restrict__ csr,
                                                    const float* __restrict__ dinv,
                                                    const float* __restrict__ bias,
                                                    float* __restrict__ out, int n) {
    int node = blockIdx.x * 32 + (threadIdx.x >> 3);
    int g = threadIdx.x & 7;            // dims g*8..g*8+7 of 64
    if (node >= n) return;
    int s = ptr[node], e = ptr[node + 1];
    float di = dinv[node];
    const h8* Tv = (const h8*)T;        // 8 h8 per row
    float acc[8] = {};
    int k = s;
    for (; k + 3 < e; k += 4) {
        int2 e0 = csr[k], e1 = csr[k + 1], e2 = csr[k + 2], e3 = csr[k + 3];
        h8 v0 = Tv[(size_t)e0.x * 8 + g];
        h8 v1 = Tv[(size_t)e1.x * 8 + g];
        h8 v2 = Tv[(size_t)e2.x * 8 + g];
        h8 v3 = Tv[(size_t)e3.x * 8 + g];
        float w0 = __int_as_float(e0.y), w1 = __int_as_float(e1.y);
        float w2 = __int_as_float(e2.y), w3 = __int_as_float(e3.y);
        #pragma unroll
        for (int j = 0; j < 8; ++j) acc[j] += w0 * (float)v0[j];
        #pragma unroll
        for (int j = 0; j < 8; ++j) acc[j] += w1 * (float)v1[j];
        #pragma unroll
        for (int j = 0; j < 8; ++j) acc[j] += w2 * (float)v2[j];
        #pragma unroll
        for (int j = 0; j < 8; ++j) acc[j] += w3 * (float)v3[j];
    }
    for (; k < e; ++k) {
        int2 e0 = csr[k];
        h8 v0 = Tv[(size_t)e0.x * 8 + g];
        float w0 = __int_as_float(e0.y);
        #pragma unroll
        for (int j = 0; j < 8; ++j) acc[j] += w0 * (float)v0[j];
    }
    h8 hs = Tv[(size_t)node * 8 + g];   // self term
    #pragma unroll
    for (int j = 0; j < 8; ++j) acc[j] += (float)hs[j];
    float4 b0 = ((const float4*)bias)[g * 2];
    float4 b1 = ((const float4*)bias)[g * 2 + 1];
    float4 o0, o1;
    o0.x = di * acc[0] + b0.x; o0.y = di * acc[1] + b0.y;
    o0.z = di * acc[2] + b0.z; o0.w = di * acc[3] + b0.w;
    o1.x = di * acc[4] + b1.x; o1.y = di * acc[5] + b1.y;
    o1.z = di * acc[6] + b1.z; o1.w = di * acc[7] + b1.w;
    ((float4*)out)[(size_t)node * 16 + g * 2] = o0;
    ((float4*)out)[(size_t)node * 16 + g * 2 + 1] = o1;
}

extern "C" void kernel_launch(void* const* d_in, const int* in_sizes, int n_in,
                              void* d_out, int out_size, void* d_ws, size_t ws_size,
                              hipStream_t stream) {
    const float* x   = (const float*)d_in[0];
    const int* eidx  = (const int*)d_in[1];
    const float* ew  = (const float*)d_in[2];
    const float* W1  = (const float*)d_in[3];
    const float* b1  = (const float*)d_in[4];
    const float* W2  = (const float*)d_in[5];
    const float* b2  = (const float*)d_in[6];
    const float* W3  = (const float*)d_in[7];
    const float* b3  = (const float*)d_in[8];

    const int N = in_sizes[0] / K_DIM;
    const int E = in_sizes[2];
    const int* erow = eidx;
    const int* ecol = eidx + E;
    const int NB = (N + 255) / 256;         // node buckets of 256
    const int NBLK = (E + EPB - 1) / EPB;   // multi-split blocks

    size_t off = 0;
    auto carve = [&](size_t bytes) {
        char* p = (char*)d_ws + off;
        off += (bytes + 255) & ~(size_t)255;
        return (void*)p;
    };
    int*   Hm   = (int*)carve((size_t)NBLK * NB * 4);
    int*   bcnt = (int*)carve((size_t)NB * 4);
    int*   bptr = (int*)carve((size_t)(NB + 1) * 4);
    int*   ptr  = (int*)carve((size_t)(N + 1) * 4);
    float* dinv = (float*)carve((size_t)N * 4);
    int2*  csr  = (int2*)carve((size_t)E * 8);
    // ebuf (pre) time-shares with Tf (layers 1-2)
    size_t ubytes = (size_t)E * 8;
    if ((size_t)N * 128 * 2 > ubytes) ubytes = (size_t)N * 128 * 2;
    void* uni = carve(ubytes);
    int2*     ebuf = (int2*)uni;
    _Float16* Tf   = (_Float16*)uni;
    _Float16* Hact = (_Float16*)carve((size_t)N * 128 * 2);  // fp16 activations
    _Float16* T3   = (_Float16*)carve((size_t)N * 64 * 2);   // fp16 layer-3 Ts
    _Float16* Wt1 = (_Float16*)carve(128 * 128 * 2);
    _Float16* Wt2 = (_Float16*)carve(128 * 128 * 2);
    _Float16* Wt3 = (_Float16*)carve(64 * 128 * 2);
    (void)ws_size;

    float* out = (float*)d_out;

    // ---- multi-split CSC build (+fused weight transpose) + canonicalize + norm ----
    mhist_kernel<<<NBLK + 160, 256, 0, stream>>>(ecol, Hm, E, NB, NBLK,
                                                 W1, W2, W3, Wt1, Wt2, Wt3);
    colscan_kernel<<<(NB + 3) / 4, 256, 0, stream>>>(Hm, bcnt, NBLK, NB);
    bscan2_kernel<<<1, 1024, 0, stream>>>(bcnt, bptr, ptr, NB, N, E);
    mscatter_kernel<<<NBLK, 256, 0, stream>>>(erow, ecol, ew, Hm, bptr, ebuf, E, NB);
    bbuild_kernel<<<NB, 256, 0, stream>>>(ebuf, bptr, csr, ptr, N);
    sortdeg_kernel<<<(N + 3) / 4, 256, 0, stream>>>(csr, ptr, dinv, N);

    int gG = (N + 127) / 128;
    int gAgg16 = (N + 15) / 16;
    int gAgg32 = (N + 31) / 32;

    // layer 1 (unroll-8 test)
    mgemm_kernel<128, false><<<gG, 256, 0, stream>>>(x, Wt1, dinv, Tf, N);
    agg128_kernel<8><<<gAgg16, 256, 0, stream>>>(Tf, ptr, csr, dinv, b1, Hact, N);
    // layer 2 (unroll-4 control)
    mgemm_kernel<128, true><<<gG, 256, 0, stream>>>(Hact, Wt2, dinv, Tf, N);
    agg128_kernel<4><<<gAgg16, 256, 0, stream>>>(Tf, ptr, csr, dinv, b2, Hact, N);
    // layer 3
    mgemm_kernel<64, true><<<gG, 256, 0, stream>>>(Hact, Wt3, dinv, T3, N);
    agg64_kernel<<<gAgg32, 256, 0, stream>>>(T3, ptr, csr, dinv, b3, out, N);
}

// Round 19
// 321.452 us; speedup vs baseline: 1.0166x; 1.0166x over previous
//
#include <hip/hip_runtime.h>
#include <hip/hip_bf16.h>
#include <hip/hip_fp16.h>

// GCN3: 3-layer GCN on MI355X. All internal feature matrices fp16 (f32 accumulate).
// out[i] = dinv[i]*(sum_e ew*Ts[row_e] + Ts[i]) + b, Ts[r] = dinv[r]*(h@W)[r]
// CSC build: LDS multi-split (256-node buckets) -> parallel column scan ->
// per-bucket counting sort -> canonical bitonic sort (bit-deterministic).
// GEMMs: fp16-input MFMA, LDS XOR-swizzled fragments.
// Aggregation: unroll-4 (measured best: beats unroll-8 and split-chain).
// Weight transpose fused into the mhist launch.

#define K_DIM 128
#define EPB 4096    // edges per multi-split block
#define BSH 8       // bucket shift: 256 nodes per bucket
#define NBMAX 512   // LDS array size for bucket counters

using h4 = __attribute__((ext_vector_type(4))) _Float16;
using h8 = __attribute__((ext_vector_type(8))) _Float16;
using f16x4 = h4;
using f16x8 = h8;
typedef float f32x4 __attribute__((ext_vector_type(4)));

// ---------------- per-block bucket histogram (LDS) + fused weight transpose ----------
__global__ __launch_bounds__(256) void mhist_kernel(const int* __restrict__ col,
                                                    int* __restrict__ Hm, int e, int nb,
                                                    int nblk,
                                                    const float* __restrict__ W1,
                                                    const float* __restrict__ W2,
                                                    const float* __restrict__ W3,
                                                    _Float16* __restrict__ Wt1,
                                                    _Float16* __restrict__ Wt2,
                                                    _Float16* __restrict__ Wt3) {
    int blk = blockIdx.x, t = threadIdx.x;
    if (blk >= nblk) {   // weight transpose blocks
        int i = (blk - nblk) * 256 + t;
        if (i < 16384) {
            int k = i / 128, c = i % 128;
            Wt1[c * 128 + k] = (_Float16)W1[i];
        } else if (i < 32768) {
            int j = i - 16384, k = j / 128, c = j % 128;
            Wt2[c * 128 + k] = (_Float16)W2[j];
        } else if (i < 40960) {
            int j = i - 32768, k = j / 64, c = j % 64;
            Wt3[c * 128 + k] = (_Float16)W3[j];
        }
        return;
    }
    __shared__ int lcnt[NBMAX];
    for (int i = t; i < nb; i += 256) lcnt[i] = 0;
    __syncthreads();
    int base = blk * EPB, end = min(base + EPB, e);
    for (int i = base + t; i < end; i += 256) atomicAdd(&lcnt[col[i] >> BSH], 1);
    __syncthreads();
    for (int i = t; i < nb; i += 256) Hm[(size_t)blk * nb + i] = lcnt[i];
}

// ---------------- column scan: per bucket, exclusive scan over blocks (one wave/col) ----
__global__ __launch_bounds__(256) void colscan_kernel(int* __restrict__ Hm,
                                                      int* __restrict__ bcnt,
                                                      int nblk, int nb) {
    int t = blockIdx.x * 4 + (threadIdx.x >> 6);   // bucket column
    int lane = threadIdx.x & 63;
    if (t >= nb) return;
    int carry = 0;
    for (int c0 = 0; c0 < nblk; c0 += 64) {
        int b = c0 + lane;
        int x = (b < nblk) ? Hm[(size_t)b * nb + t] : 0;
        int v = x;
        #pragma unroll
        for (int d = 1; d < 64; d <<= 1) {
            int y = __shfl_up(v, d, 64);
            if (lane >= d) v += y;
        }
        if (b < nblk) Hm[(size_t)b * nb + t] = carry + v - x;  // exclusive within column
        carry += __shfl(v, 63, 64);
    }
    if (lane == 0) bcnt[t] = carry;   // bucket total
}

// ---------------- single-block scan of bucket totals -> bptr ----------------
__global__ __launch_bounds__(1024) void bscan2_kernel(const int* __restrict__ bcnt,
                                                      int* __restrict__ bptr,
                                                      int* __restrict__ nodeptr,
                                                      int nb, int nN, int etot) {
    __shared__ int wsum[16];
    int t = threadIdx.x, lane = t & 63, wid = t >> 6;
    int x = (t < nb) ? bcnt[t] : 0;
    int v = x;
    #pragma unroll
    for (int d = 1; d < 64; d <<= 1) {
        int y = __shfl_up(v, d, 64);
        if (lane >= d) v += y;
    }
    if (lane == 63) wsum[wid] = v;
    __syncthreads();
    if (wid == 0) {
        int s = (lane < 16) ? wsum[lane] : 0;
        #pragma unroll
        for (int d = 1; d < 16; d <<= 1) {
            int y = __shfl_up(s, d, 64);
            if (lane >= d) s += y;
        }
        if (lane < 16) wsum[lane] = s;
    }
    __syncthreads();
    int woff = (wid > 0) ? wsum[wid - 1] : 0;
    if (t < nb) bptr[t] = v + woff - x;
    if (t == 0) { bptr[nb] = etot; nodeptr[nN] = etot; }
}

// ---------------- multi-split scatter (bptr folded in): bucket-grouped writes ----
__global__ __launch_bounds__(256) void mscatter_kernel(const int* __restrict__ row,
                                                       const int* __restrict__ col,
                                                       const float* __restrict__ ew,
                                                       const int* __restrict__ Hm,
                                                       const int* __restrict__ bptr,
                                                       int2* __restrict__ ebuf,
                                                       int e, int nb) {
    __shared__ int2 sbuf[EPB];               // 32 KB
    __shared__ unsigned short sbkt[EPB];     // 8 KB
    __shared__ int lcnt[NBMAX], lbase[NBMAX], lfill[NBMAX], garr[NBMAX];  // 8 KB
    int blk = blockIdx.x, t = threadIdx.x, lane = t & 63, wid = t >> 6;
    int base = blk * EPB, end = min(base + EPB, e);
    int cnt = end - base;
    if (cnt <= 0) return;
    for (int i = t; i < nb; i += 256) {
        garr[i] = Hm[(size_t)blk * nb + i] + bptr[i];   // fold global bucket base
        lcnt[i] = 0;
    }
    __syncthreads();
    for (int i = base + t; i < end; i += 256) atomicAdd(&lcnt[col[i] >> BSH], 1);
    __syncthreads();
    if (wid == 0) {   // wave-0 exclusive scan of lcnt -> lbase/lfill
        int carry = 0;
        for (int c0 = 0; c0 < nb; c0 += 64) {
            int idx = c0 + lane;
            int x = (idx < nb) ? lcnt[idx] : 0;
            int v = x;
            #pragma unroll
            for (int d = 1; d < 64; d <<= 1) {
                int y = __shfl_up(v, d, 64);
                if (lane >= d) v += y;
            }
            if (idx < nb) { lbase[idx] = carry + v - x; lfill[idx] = carry + v - x; }
            carry += __shfl(v, 63, 64);
        }
    }
    __syncthreads();
    for (int i = base + t; i < end; i += 256) {
        int c = col[i];
        int b = c >> BSH;
        int p = atomicAdd(&lfill[b], 1);
        sbuf[p] = make_int2(row[i] | ((c & 255) << 20), __float_as_int(ew[i]));
        sbkt[p] = (unsigned short)b;
    }
    __syncthreads();
    for (int j = t; j < cnt; j += 256) {   // bucket-grouped contiguous runs
        int b = sbkt[j];
        ebuf[garr[b] + (j - lbase[b])] = sbuf[j];
    }
}

// ---------------- per-bucket counting sort (256 bins) into final CSC + node ptr ----------
__global__ __launch_bounds__(256) void bbuild_kernel(const int2* __restrict__ ebuf,
                                                     const int* __restrict__ bptr,
                                                     int2* __restrict__ csr,
                                                     int* __restrict__ ptr, int n) {
    __shared__ int cnt[256];
    __shared__ int fil[256];
    __shared__ int wtot[4];
    int b = blockIdx.x, t = threadIdx.x, lane = t & 63, wid = t >> 6;
    int s = bptr[b], e = bptr[b + 1];
    cnt[t] = 0;
    __syncthreads();
    for (int k = s + t; k < e; k += 256) atomicAdd(&cnt[(ebuf[k].x >> 20) & 255], 1);
    __syncthreads();
    int x = cnt[t];
    int v = x;
    #pragma unroll
    for (int d = 1; d < 64; d <<= 1) {
        int y = __shfl_up(v, d, 64);
        if (lane >= d) v += y;
    }
    if (lane == 63) wtot[wid] = v;
    __syncthreads();
    int woff = 0;
    for (int j = 0; j < wid; ++j) woff += wtot[j];
    int excl = woff + v - x;
    fil[t] = excl;
    int node = b * 256 + t;
    if (node < n) ptr[node] = s + excl;
    __syncthreads();
    for (int k = s + t; k < e; k += 256) {
        int2 vv = ebuf[k];
        int c = (vv.x >> 20) & 255;
        int p = atomicAdd(&fil[c], 1);
        csr[s + p] = make_int2(vv.x & 0xFFFFF, vv.y);
    }
}

// ---------------- canonicalize + dinv: one wave per node, bitonic in-register sort ----
__global__ __launch_bounds__(256) void sortdeg_kernel(int2* __restrict__ csr,
                                                      const int* __restrict__ ptr,
                                                      float* __restrict__ dinv, int n) {
    int node = blockIdx.x * 4 + (threadIdx.x >> 6);
    int lane = threadIdx.x & 63;
    if (node >= n) return;
    int s = ptr[node], e = ptr[node + 1];
    int len = e - s;
    if (len <= 64) {
        int mx = 0x7FFFFFFF;
        unsigned my = 0xFFFFFFFFu;   // sentinel = +inf key
        if (lane < len) {
            int2 v = csr[s + lane];
            mx = v.x; my = (unsigned)v.y;
        }
        #pragma unroll
        for (int k = 2; k <= 64; k <<= 1) {
            #pragma unroll
            for (int j = k >> 1; j > 0; j >>= 1) {
                int ox = __shfl_xor(mx, j, 64);
                unsigned oy = (unsigned)__shfl_xor((int)my, j, 64);
                bool up = ((lane & k) == 0);
                bool lower = ((lane & j) == 0);
                bool keep_min = (up == lower);
                bool me_gt  = (mx > ox) || (mx == ox && my > oy);
                bool oth_gt = (ox > mx) || (ox == mx && oy > my);
                bool take = keep_min ? me_gt : oth_gt;
                if (take) { mx = ox; my = oy; }
            }
        }
        if (lane < len) csr[s + lane] = make_int2(mx, (int)my);
        float w = (lane < len) ? __uint_as_float(my) : 0.f;
        #pragma unroll
        for (int d = 32; d; d >>= 1) w += __shfl_xor(w, d, 64);
        if (lane == 0) dinv[node] = rsqrtf(1.0f + w);
    } else {
        if (lane == 0) {  // ultra-rare fallback
            for (int k = s + 1; k < e; ++k) {
                int2 key = csr[k];
                int j = k - 1;
                while (j >= s) {
                    int2 cj = csr[j];
                    bool gt = (cj.x > key.x) ||
                              (cj.x == key.x && (unsigned)cj.y > (unsigned)key.y);
                    if (!gt) break;
                    csr[j + 1] = cj;
                    --j;
                }
                csr[j + 1] = key;
            }
            float sum = 1.0f;
            for (int k = s; k < e; ++k) sum += __int_as_float(csr[k].y);
            dinv[node] = rsqrtf(sum);
        }
    }
}

// ---------------- MFMA GEMM: Ts[r,:] = dinv[r] * (A[r,:] @ W) ----------------
template <int DOUT, bool FP16IN>
__global__ __launch_bounds__(256) void mgemm_kernel(const void* __restrict__ Ap,
                                                    const _Float16* __restrict__ Wt,
                                                    const float* __restrict__ dinv,
                                                    _Float16* __restrict__ Tout, int nrows) {
    constexpr int BM = 128;
    constexpr int NCB = DOUT / 16;
    __shared__ f16x8 Als[BM * 16];
    __shared__ f16x8 Wls[DOUT * 16];
    int t = threadIdx.x;
    int row0 = blockIdx.x * BM;

    const f16x8* Wt8 = (const f16x8*)Wt;
    for (int i = t; i < DOUT * 16; i += 256) {
        int r = i >> 4, s = i & 15;
        Wls[r * 16 + (s ^ (r & 7))] = Wt8[i];
    }
    if constexpr (FP16IN) {
        const f16x8* A8 = (const f16x8*)Ap;
        for (int i = t; i < BM * 16; i += 256) {
            int r = i >> 4, s = i & 15;
            f16x8 v = {};
            int gr = row0 + r;
            if (gr < nrows) v = A8[(size_t)gr * 16 + s];
            Als[r * 16 + (s ^ (r & 7))] = v;
        }
    } else {
        const float* A = (const float*)Ap;
        f16x4* Als4 = (f16x4*)Als;
        for (int i = t; i < BM * 32; i += 256) {
            int r = i >> 5, c4 = i & 31;
            float4 v = make_float4(0.f, 0.f, 0.f, 0.f);
            int gr = row0 + r;
            if (gr < nrows) v = ((const float4*)(A + (size_t)gr * 128))[c4];
            f16x4 h;
            h[0] = (_Float16)v.x; h[1] = (_Float16)v.y;
            h[2] = (_Float16)v.z; h[3] = (_Float16)v.w;
            Als4[r * 32 + (c4 ^ ((r & 7) << 1))] = h;
        }
    }
    __syncthreads();

    int w = t >> 6, l = t & 63;
    int lcol = l & 15, lk = l >> 4;
    int wr0 = w * 32;

    f16x8 af[2][4];
    #pragma unroll
    for (int rb = 0; rb < 2; ++rb) {
        int r = wr0 + rb * 16 + lcol;
        #pragma unroll
        for (int kc = 0; kc < 4; ++kc) {
            int s = kc * 4 + lk;
            af[rb][kc] = Als[r * 16 + (s ^ (r & 7))];
        }
    }

    f32x4 acc[2][NCB] = {};
    #pragma unroll
    for (int cb = 0; cb < NCB; ++cb) {
        int c = cb * 16 + lcol;
        f16x8 bf[4];
        #pragma unroll
        for (int kc = 0; kc < 4; ++kc) {
            int s = kc * 4 + lk;
            bf[kc] = Wls[c * 16 + (s ^ (c & 7))];
        }
        #pragma unroll
        for (int rb = 0; rb < 2; ++rb) {
            #pragma unroll
            for (int kc = 0; kc < 4; ++kc)
                acc[rb][cb] = __builtin_amdgcn_mfma_f32_16x16x32_f16(
                    af[rb][kc], bf[kc], acc[rb][cb], 0, 0, 0);
        }
    }

    #pragma unroll
    for (int rb = 0; rb < 2; ++rb) {
        #pragma unroll
        for (int reg = 0; reg < 4; ++reg) {
            int gr = row0 + wr0 + rb * 16 + lk * 4 + reg;
            if (gr >= nrows) continue;
            float di = dinv[gr];
            #pragma unroll
            for (int cb = 0; cb < NCB; ++cb) {
                int c = cb * 16 + lcol;
                Tout[(size_t)gr * DOUT + c] = (_Float16)(acc[rb][cb][reg] * di);
            }
        }
    }
}

// ---------------- aggregation, D=128 fp16 T -> fp16 H (relu): 16 lanes/node, unroll-4 ----
__global__ __launch_bounds__(256) void agg128_kernel(const _Float16* __restrict__ T,
                                                     const int* __restrict__ ptr,
                                                     const int2* __restrict__ csr,
                                                     const float* __restrict__ dinv,
                                                     const float* __restrict__ bias,
                                                     _Float16* __restrict__ out, int n) {
    int node = blockIdx.x * 16 + (threadIdx.x >> 4);
    int g = threadIdx.x & 15;
    if (node >= n) return;
    int s = ptr[node], e = ptr[node + 1];
    float di = dinv[node];
    const h8* Tv = (const h8*)T;
    float acc[8] = {};
    int k = s;
    for (; k + 3 < e; k += 4) {
        int2 e0 = csr[k], e1 = csr[k + 1], e2 = csr[k + 2], e3 = csr[k + 3];
        h8 v0 = Tv[(size_t)e0.x * 16 + g];
        h8 v1 = Tv[(size_t)e1.x * 16 + g];
        h8 v2 = Tv[(size_t)e2.x * 16 + g];
        h8 v3 = Tv[(size_t)e3.x * 16 + g];
        float w0 = __int_as_float(e0.y), w1 = __int_as_float(e1.y);
        float w2 = __int_as_float(e2.y), w3 = __int_as_float(e3.y);
        #pragma unroll
        for (int j = 0; j < 8; ++j) acc[j] += w0 * (float)v0[j];
        #pragma unroll
        for (int j = 0; j < 8; ++j) acc[j] += w1 * (float)v1[j];
        #pragma unroll
        for (int j = 0; j < 8; ++j) acc[j] += w2 * (float)v2[j];
        #pragma unroll
        for (int j = 0; j < 8; ++j) acc[j] += w3 * (float)v3[j];
    }
    for (; k < e; ++k) {
        int2 e0 = csr[k];
        h8 v0 = Tv[(size_t)e0.x * 16 + g];
        float w0 = __int_as_float(e0.y);
        #pragma unroll
        for (int j = 0; j < 8; ++j) acc[j] += w0 * (float)v0[j];
    }
    h8 hs = Tv[(size_t)node * 16 + g];  // self term: + Ts[i]
    #pragma unroll
    for (int j = 0; j < 8; ++j) acc[j] += (float)hs[j];
    float4 b0 = ((const float4*)bias)[g * 2];
    float4 b1 = ((const float4*)bias)[g * 2 + 1];
    float bb[8] = {b0.x, b0.y, b0.z, b0.w, b1.x, b1.y, b1.z, b1.w};
    h8 o;
    #pragma unroll
    for (int j = 0; j < 8; ++j) {
        float v = di * acc[j] + bb[j];
        o[j] = (_Float16)fmaxf(v, 0.f);   // relu
    }
    ((h8*)out)[(size_t)node * 16 + g] = o;
}

// ---------------- aggregation, D=64 fp16 T -> f32 out (layer 3): 8 lanes/node ----
__global__ __launch_bounds__(256) void agg64_kernel(const _Float16* __restrict__ T,
                                                    const int* __restrict__ ptr,
                                                    const int2* __restrict__ csr,
                                                    const float* __restrict__ dinv,
                                                    const float* __restrict__ bias,
                                                    float* __restrict__ out, int n) {
    int node = blockIdx.x * 32 + (threadIdx.x >> 3);
    int g = threadIdx.x & 7;            // dims g*8..g*8+7 of 64
    if (node >= n) return;
    int s = ptr[node], e = ptr[node + 1];
    float di = dinv[node];
    const h8* Tv = (const h8*)T;        // 8 h8 per row
    float acc[8] = {};
    int k = s;
    for (; k + 3 < e; k += 4) {
        int2 e0 = csr[k], e1 = csr[k + 1], e2 = csr[k + 2], e3 = csr[k + 3];
        h8 v0 = Tv[(size_t)e0.x * 8 + g];
        h8 v1 = Tv[(size_t)e1.x * 8 + g];
        h8 v2 = Tv[(size_t)e2.x * 8 + g];
        h8 v3 = Tv[(size_t)e3.x * 8 + g];
        float w0 = __int_as_float(e0.y), w1 = __int_as_float(e1.y);
        float w2 = __int_as_float(e2.y), w3 = __int_as_float(e3.y);
        #pragma unroll
        for (int j = 0; j < 8; ++j) acc[j] += w0 * (float)v0[j];
        #pragma unroll
        for (int j = 0; j < 8; ++j) acc[j] += w1 * (float)v1[j];
        #pragma unroll
        for (int j = 0; j < 8; ++j) acc[j] += w2 * (float)v2[j];
        #pragma unroll
        for (int j = 0; j < 8; ++j) acc[j] += w3 * (float)v3[j];
    }
    for (; k < e; ++k) {
        int2 e0 = csr[k];
        h8 v0 = Tv[(size_t)e0.x * 8 + g];
        float w0 = __int_as_float(e0.y);
        #pragma unroll
        for (int j = 0; j < 8; ++j) acc[j] += w0 * (float)v0[j];
    }
    h8 hs = Tv[(size_t)node * 8 + g];   // self term
    #pragma unroll
    for (int j = 0; j < 8; ++j) acc[j] += (float)hs[j];
    float4 b0 = ((const float4*)bias)[g * 2];
    float4 b1 = ((const float4*)bias)[g * 2 + 1];
    float4 o0, o1;
    o0.x = di * acc[0] + b0.x; o0.y = di * acc[1] + b0.y;
    o0.z = di * acc[2] + b0.z; o0.w = di * acc[3] + b0.w;
    o1.x = di * acc[4] + b1.x; o1.y = di * acc[5] + b1.y;
    o1.z = di * acc[6] + b1.z; o1.w = di * acc[7] + b1.w;
    ((float4*)out)[(size_t)node * 16 + g * 2] = o0;
    ((float4*)out)[(size_t)node * 16 + g * 2 + 1] = o1;
}

extern "C" void kernel_launch(void* const* d_in, const int* in_sizes, int n_in,
                              void* d_out, int out_size, void* d_ws, size_t ws_size,
                              hipStream_t stream) {
    const float* x   = (const float*)d_in[0];
    const int* eidx  = (const int*)d_in[1];
    const float* ew  = (const float*)d_in[2];
    const float* W1  = (const float*)d_in[3];
    const float* b1  = (const float*)d_in[4];
    const float* W2  = (const float*)d_in[5];
    const float* b2  = (const float*)d_in[6];
    const float* W3  = (const float*)d_in[7];
    const float* b3  = (const float*)d_in[8];

    const int N = in_sizes[0] / K_DIM;
    const int E = in_sizes[2];
    const int* erow = eidx;
    const int* ecol = eidx + E;
    const int NB = (N + 255) / 256;         // node buckets of 256
    const int NBLK = (E + EPB - 1) / EPB;   // multi-split blocks

    size_t off = 0;
    auto carve = [&](size_t bytes) {
        char* p = (char*)d_ws + off;
        off += (bytes + 255) & ~(size_t)255;
        return (void*)p;
    };
    int*   Hm   = (int*)carve((size_t)NBLK * NB * 4);
    int*   bcnt = (int*)carve((size_t)NB * 4);
    int*   bptr = (int*)carve((size_t)(NB + 1) * 4);
    int*   ptr  = (int*)carve((size_t)(N + 1) * 4);
    float* dinv = (float*)carve((size_t)N * 4);
    int2*  csr  = (int2*)carve((size_t)E * 8);
    // ebuf (pre) time-shares with Tf (layers 1-2)
    size_t ubytes = (size_t)E * 8;
    if ((size_t)N * 128 * 2 > ubytes) ubytes = (size_t)N * 128 * 2;
    void* uni = carve(ubytes);
    int2*     ebuf = (int2*)uni;
    _Float16* Tf   = (_Float16*)uni;
    _Float16* Hact = (_Float16*)carve((size_t)N * 128 * 2);  // fp16 activations
    _Float16* T3   = (_Float16*)carve((size_t)N * 64 * 2);   // fp16 layer-3 Ts
    _Float16* Wt1 = (_Float16*)carve(128 * 128 * 2);
    _Float16* Wt2 = (_Float16*)carve(128 * 128 * 2);
    _Float16* Wt3 = (_Float16*)carve(64 * 128 * 2);
    (void)ws_size;

    float* out = (float*)d_out;

    // ---- multi-split CSC build (+fused weight transpose) + canonicalize + norm ----
    mhist_kernel<<<NBLK + 160, 256, 0, stream>>>(ecol, Hm, E, NB, NBLK,
                                                 W1, W2, W3, Wt1, Wt2, Wt3);
    colscan_kernel<<<(NB + 3) / 4, 256, 0, stream>>>(Hm, bcnt, NBLK, NB);
    bscan2_kernel<<<1, 1024, 0, stream>>>(bcnt, bptr, ptr, NB, N, E);
    mscatter_kernel<<<NBLK, 256, 0, stream>>>(erow, ecol, ew, Hm, bptr, ebuf, E, NB);
    bbuild_kernel<<<NB, 256, 0, stream>>>(ebuf, bptr, csr, ptr, N);
    sortdeg_kernel<<<(N + 3) / 4, 256, 0, stream>>>(csr, ptr, dinv, N);

    int gG = (N + 127) / 128;
    int gAgg16 = (N + 15) / 16;
    int gAgg32 = (N + 31) / 32;

    // layer 1
    mgemm_kernel<128, false><<<gG, 256, 0, stream>>>(x, Wt1, dinv, Tf, N);
    agg128_kernel<<<gAgg16, 256, 0, stream>>>(Tf, ptr, csr, dinv, b1, Hact, N);
    // layer 2
    mgemm_kernel<128, true><<<gG, 256, 0, stream>>>(Hact, Wt2, dinv, Tf, N);
    agg128_kernel<<<gAgg16, 256, 0, stream>>>(Tf, ptr, csr, dinv, b2, Hact, N);
    // layer 3
    mgemm_kernel<64, true><<<gG, 256, 0, stream>>>(Hact, Wt3, dinv, T3, N);
    agg64_kernel<<<gAgg32, 256, 0, stream>>>(T3, ptr, csr, dinv, b3, out, N);
}